// Round 18
// baseline (128.474 us; speedup 1.0000x reference)
//
#include <hip/hip_runtime.h>

// PairWeightedAveraging: m[1,S,N,Dm], z[1,N,N,Dz] -> out[1,S,N,Dm]
// S=256 N=512 Dm=64 Dz=128 H=8 HD=32
// Pipeline (all bf16 MFMA):
//  k0: pre-swizzle [Wm|Wg], Wo, and W'=znw*Wz (split hi/lo bf16) frag tables
//  k1_fused: bias MFMA in LDS + row softmax -> wf (512 thr, verbatim R17 body;
//    split back out for per-kernel timing)
//  k2_fused (R17->R18): LN(m) in-register + v = mn @ Wm; vf tile accumulated
//    in PADDED LDS (stride 34 u16) and written out with fully-coalesced
//    16B/lane stores. R17 evidence: k12 occupancy-independent at 88us ->
//    L2-transaction-bound; old vf scatter was 8B/lane @ 64B stride (~8x
//    transaction inflation on 64MB).
//  k3_fused: UNCHANGED verified-best.

#define S_DIM 256
#define N_DIM 512
#define DM 64
#define DZ 128
#define NH 8
#define HD 32
#define HK 256
#define NP 8192  // S_DIM*HD
#define BKP 32   // K-panel depth
#define JT_N 16  // 512 / BKP

typedef unsigned int   u32;
typedef unsigned short u16;
typedef __bf16 bf16x8 __attribute__((ext_vector_type(8)));
typedef float  f32x4  __attribute__((ext_vector_type(4)));
typedef u32    u32x4  __attribute__((ext_vector_type(4)));

__device__ __forceinline__ u16 f2bf(float f) {
  u32 u = __builtin_bit_cast(u32, f);
  return (u16)((u + 0x7FFFu + ((u >> 16) & 1u)) >> 16);  // RNE
}
__device__ __forceinline__ float bf2f(u16 h) {
  u32 u = ((u32)h) << 16;
  return __builtin_bit_cast(float, u);
}
__device__ __forceinline__ u32 pack2(float a, float b) {
  return (u32)f2bf(a) | ((u32)f2bf(b) << 16);
}
__device__ __forceinline__ bf16x8 ld8(const u16* p) {
  return __builtin_bit_cast(bf16x8, *(const u32x4*)p);
}
__device__ __forceinline__ f32x4 mfma16(bf16x8 a, bf16x8 b, f32x4 c) {
  return __builtin_amdgcn_mfma_f32_16x16x32_bf16(a, b, c, 0, 0, 0);
}
__device__ __forceinline__ void gload_lds16(const void* gsrc, void* ldst) {
  __builtin_amdgcn_global_load_lds(
      (const __attribute__((address_space(1))) void*)gsrc,
      (__attribute__((address_space(3))) void*)ldst, 16, 0, 0);
}
__device__ __forceinline__ float fast_sigmoid(float x) {
  float r;
  asm("v_rcp_f32 %0, %1" : "=v"(r) : "v"(1.f + __expf(-x)));
  return r;
}
// panel byte-offset swizzle (involution; permutes 16B chunks within 8 rows of 64B)
__device__ __forceinline__ int swz(int lin) { return lin ^ (((lin >> 7) & 3) << 4); }

#define BARRIER() do { asm volatile("" ::: "memory"); \
                       __builtin_amdgcn_s_barrier();  \
                       asm volatile("" ::: "memory"); } while (0)

// ---------------- k0: weight fragment tables ----------------
__global__ __launch_bounds__(256) void k0_prep(
    const float* __restrict__ Wm, const float* __restrict__ Wg,
    const float* __restrict__ Wo, const float* __restrict__ znw,
    const float* __restrict__ znb, const float* __restrict__ Wz,
    u16* __restrict__ wmg, u16* __restrict__ wof,
    u16* __restrict__ wzf, float* __restrict__ t1c) {
  const int idx = blockIdx.x * 256 + threadIdx.x;
  if (idx < 32768) {
    const int t = idx & 7, lane = (idx >> 3) & 63, ks = (idx >> 9) & 1, cb = idx >> 10;
    const int c = cb * 16 + (lane & 15);
    const int k = ks * 32 + ((lane >> 4) & 3) * 8 + t;
    const float v = (c < HK) ? Wm[k * HK + c] : Wg[k * HK + (c - HK)];
    wmg[idx] = f2bf(v);
  } else if (idx < 32768 + 16384) {
    const int j = idx - 32768;
    const int t = j & 7, lane = (j >> 3) & 63, ks = (j >> 9) & 7, cb = j >> 12;
    const int c = cb * 16 + (lane & 15);
    const int hk = ks * 32 + ((lane >> 4) & 3) * 8 + t;
    wof[j] = f2bf(Wo[hk * DM + c]);
  } else if (idx < 49152 + 4096) {
    const int q = idx - 49152;
    const int t = q & 7, lane = (q >> 3) & 63, p = (q >> 9) & 1, ks = q >> 10;
    const int h = lane & 15;
    const int k = ks * 32 + ((lane >> 4) & 3) * 8 + t;
    u16 val = 0;
    if (h < NH) {
      const float wp = znw[k] * Wz[k * NH + h];
      const u16 hi = f2bf(wp);
      val = (p == 0) ? hi : f2bf(wp - bf2f(hi));
    }
    wzf[q] = val;
  } else if (idx < 49152 + 4096 + 16) {
    const int q = idx - 49152 - 4096;  // 0..15
    const int h = q & 7;
    float s = 0.f;
    for (int c = 0; c < DZ; ++c)
      s += ((q < 8) ? znw[c] : znb[c]) * Wz[c * NH + h];
    t1c[q] = s;
  }
}

// ---------------- k1_fused: bias MFMA in LDS + row softmax -> wf ------------
// 512 threads; 8 waves x 16 rows = 128 rows/pass, 4 passes; softmax = one
// head per wave. Verbatim R17 k1 body.
__global__ __launch_bounds__(512, 4) void k1_fused(
    const float* __restrict__ z, const u16* __restrict__ wzf,
    const float* __restrict__ t1c, u16* __restrict__ wout) {
  __shared__ __attribute__((aligned(16))) float sB[NH][N_DIM + 4];
  const int tid = threadIdx.x, lane = tid & 63, wv = tid >> 6;  // wv 0..7
  const int i = blockIdx.x;
  const int h16 = lane & 15;
  const float t1 = t1c[h16 & 7], cst = t1c[8 + (h16 & 7)];

  for (int jj = 0; jj < 4; ++jj) {
    const float* zp = z + ((size_t)i * N_DIM + jj * 128 + wv * 16
                           + (lane & 15)) * DZ + ((lane >> 4) & 3) * 8;
    f32x4 acc = (f32x4){0.f, 0.f, 0.f, 0.f};
    float sum = 0.f, sq = 0.f;
    #pragma unroll
    for (int ks = 0; ks < 4; ++ks) {
      const float4 v0 = *(const float4*)(zp + ks * 32);
      const float4 v1 = *(const float4*)(zp + ks * 32 + 4);
      const float xs[8] = {v0.x, v0.y, v0.z, v0.w, v1.x, v1.y, v1.z, v1.w};
      bf16x8 zh, zl;
      #pragma unroll
      for (int t = 0; t < 8; ++t) {
        sum += xs[t]; sq += xs[t] * xs[t];
        const u16 hv = f2bf(xs[t]);
        ((u16*)&zh)[t] = hv;
        ((u16*)&zl)[t] = f2bf(xs[t] - bf2f(hv));
      }
      const bf16x8 wh = ld8(wzf + (ks * 2 + 0) * 512 + lane * 8);
      const bf16x8 wl = ld8(wzf + (ks * 2 + 1) * 512 + lane * 8);
      acc = mfma16(zh, wh, acc);
      acc = mfma16(zl, wh, acc);
      acc = mfma16(zh, wl, acc);
    }
    sum += __shfl_xor(sum, 16, 64); sum += __shfl_xor(sum, 32, 64);
    sq  += __shfl_xor(sq, 16, 64);  sq  += __shfl_xor(sq, 32, 64);
    const float mu = sum * (1.f / DZ);
    const float rs = rsqrtf(sq * (1.f / DZ) - mu * mu + 1e-5f);
    #pragma unroll
    for (int rg = 0; rg < 4; ++rg) {
      const int r = ((lane >> 4) & 3) * 4 + rg;
      const float mur = __shfl(mu, r, 64);
      const float rsr = __shfl(rs, r, 64);
      const float bv = rsr * (acc[rg] - mur * t1) + cst;
      if (h16 < NH) sB[h16][jj * 128 + wv * 16 + r] = bv;
    }
  }
  __syncthreads();

  // softmax: wave wv handles head wv; lane owns j=lane*8..+8
  {
    const int h = wv;
    const float* bp = &sB[h][lane * 8];
    const float4 v0 = *(const float4*)bp;
    const float4 v1 = *(const float4*)(bp + 4);
    float xs[8] = {v0.x, v0.y, v0.z, v0.w, v1.x, v1.y, v1.z, v1.w};
    float mx = xs[0];
    #pragma unroll
    for (int t = 1; t < 8; ++t) mx = fmaxf(mx, xs[t]);
    #pragma unroll
    for (int off = 32; off; off >>= 1) mx = fmaxf(mx, __shfl_xor(mx, off, 64));
    float sm = 0.f;
    #pragma unroll
    for (int t = 0; t < 8; ++t) { xs[t] = __expf(xs[t] - mx); sm += xs[t]; }
    #pragma unroll
    for (int off = 32; off; off >>= 1) sm += __shfl_xor(sm, off, 64);
    const float inv = 1.f / sm;
    u32x4 pk;
    pk[0] = pack2(xs[0] * inv, xs[1] * inv);
    pk[1] = pack2(xs[2] * inv, xs[3] * inv);
    pk[2] = pack2(xs[4] * inv, xs[5] * inv);
    pk[3] = pack2(xs[6] * inv, xs[7] * inv);
    *(u32x4*)(wout + (((size_t)(h * JT_N + (lane >> 2)) * N_DIM + i) << 5)
              + (lane & 3) * 8) = pk;
  }
}

// ---------------- k2_fused: LN(m) + v = mn @ Wm, LDS-staged coalesced vf ----
// 512 threads; 8 waves x 16 rows = 128 rows/block; 1024 blocks.
// MFMA outputs land in padded LDS sv[32 panels][32 np][34], then the block
// writes the 64KB tile with fully-coalesced 16B/lane stores.
// Block row base = bid*128 -> s0 = bid>>2 fixed, jt base = (bid&3)*4.
__global__ __launch_bounds__(512, 2) void k2_fused(
    const float* __restrict__ m, const float* __restrict__ mnw,
    const float* __restrict__ mnb, const u16* __restrict__ wmg,
    u16* __restrict__ mn, u16* __restrict__ vf) {
  __shared__ u16 sv[32 * 32 * 34];  // 69632 B, padded stride 34 u16
  __shared__ float swt[DM], sbs[DM];
  const int tid = threadIdx.x, lane = tid & 63, wv = tid >> 6;  // wv 0..7
  if (tid < DM) { swt[tid] = mnw[tid]; sbs[tid] = mnb[tid]; }
  __syncthreads();
  const int q = (lane >> 4) & 3;
  const int bid = blockIdx.x;                 // 0..1023
  const int rbase = (bid * 8 + wv) * 16;
  const int r = rbase + (lane & 15);

  const float* mp = m + (size_t)r * DM + q * 8;
  const float4 va = *(const float4*)(mp);
  const float4 vb = *(const float4*)(mp + 4);
  const float4 vc = *(const float4*)(mp + 32);
  const float4 vd = *(const float4*)(mp + 36);
  const float x0[8] = {va.x, va.y, va.z, va.w, vb.x, vb.y, vb.z, vb.w};
  const float x1[8] = {vc.x, vc.y, vc.z, vc.w, vd.x, vd.y, vd.z, vd.w};
  float sum = 0.f, sq = 0.f;
  #pragma unroll
  for (int t = 0; t < 8; ++t) {
    sum += x0[t] + x1[t];
    sq  += x0[t] * x0[t] + x1[t] * x1[t];
  }
  sum += __shfl_xor(sum, 16, 64); sum += __shfl_xor(sum, 32, 64);
  sq  += __shfl_xor(sq, 16, 64);  sq  += __shfl_xor(sq, 32, 64);
  const float mu = sum * (1.f / DM);
  const float rs = rsqrtf(sq * (1.f / DM) - mu * mu + 1e-5f);

  bf16x8 a0, a1;
  #pragma unroll
  for (int t = 0; t < 8; ++t) {
    const int c0 = q * 8 + t, c1 = q * 8 + 32 + t;
    ((u16*)&a0)[t] = f2bf((x0[t] - mu) * rs * swt[c0] + sbs[c0]);
    ((u16*)&a1)[t] = f2bf((x1[t] - mu) * rs * swt[c1] + sbs[c1]);
  }
  *(u32x4*)(mn + (size_t)r * DM + q * 8)      = __builtin_bit_cast(u32x4, a0);
  *(u32x4*)(mn + (size_t)r * DM + q * 8 + 32) = __builtin_bit_cast(u32x4, a1);

  // v projection -> padded LDS
  // wave's output rows: j0_local = wv*16 + q*4 + rg -> jtl = wv>>1,
  // jl = (wv&1)*16 + q*4 + rg.
  const u16* bp = wmg + lane * 8;
  const int jtl = wv >> 1;
  const int jl0 = (wv & 1) * 16 + q * 4;
  #pragma unroll
  for (int cb = 0; cb < 16; ++cb) {
    f32x4 acc = (f32x4){0.f, 0.f, 0.f, 0.f};
    acc = mfma16(a0, ld8(bp + cb * 1024), acc);
    acc = mfma16(a1, ld8(bp + cb * 1024 + 512), acc);
    const int c = cb * 16 + (lane & 15);
    const int h = c >> 5, k = c & 31;
    ushort4 pk;
    pk.x = f2bf(acc[0]); pk.y = f2bf(acc[1]);
    pk.z = f2bf(acc[2]); pk.w = f2bf(acc[3]);
    *(ushort4*)(&sv[((h * 4 + jtl) * 32 + k) * 34 + jl0]) = pk;
  }
  __syncthreads();

  // coalesced write-out: 4096 16B chunks, 8 per thread.
  // chunk ci: panel p = ci>>7 (p = h*4+jtl), w = ci&127 (k = w>>2, j=(w&3)*8)
  const int s0 = bid >> 2;
  const int jtg0 = (bid & 3) * 4;
  #pragma unroll
  for (int cidx = 0; cidx < 8; ++cidx) {
    const int ci = tid + cidx * 512;
    const int p = ci >> 7, w = ci & 127;
    const int h = p >> 2, jtl2 = p & 3;
    const int k = w >> 2, j = (w & 3) * 8;
    const u32x4 val = *(const u32x4*)(&sv[(p * 32 + k) * 34 + j]);
    u16* dst = vf + ((size_t)(h * JT_N + jtg0 + jtl2) * NP << 5)
               + s0 * 1024 + w * 8;
    *(u32x4*)dst = val;
  }
}

// ---------------- k3_fused: o = w@v over all heads + gate + Wo projection ----
// UNCHANGED verified-best.
__global__ __launch_bounds__(256, 4) void k3_fused(
    const u16* __restrict__ wf, const u16* __restrict__ vf,
    const u16* __restrict__ mn, const u16* __restrict__ wmg,
    const u16* __restrict__ wof, float* __restrict__ out) {
  __shared__ __attribute__((aligned(16))) u16 ring[4][4096];  // 8KB/slot: A|B
  const int tid = threadIdx.x, lane = tid & 63, wv = tid >> 6;
  const int q = (lane >> 4) & 3;
  const int wr = wv >> 1, wc = wv & 1;
  const int bid = blockIdx.x;            // 0..1023
  const int xcd = bid & 7, j = bid >> 3; // j 0..127
  const int xt = xcd * 16 + (j >> 3);    // np-tile 0..127 (partitioned by XCD)
  const int yt = j & 7;                  // i-tile 0..7 (consecutive per panel)
  const int i0 = yt * 64;
  const int n0 = xt * 64;
  const int s  = xt * 2 + wc;

  const int sbA = wv * 1024;
  const int soA = swz(sbA + lane * 16);
  const int soB = swz(sbA + lane * 16);

  int offA[2], offB[2];
  #pragma unroll
  for (int f = 0; f < 2; ++f)
    offA[f] = swz((wr * 32 + f * 16 + (lane & 15)) * 64 + q * 16);
  #pragma unroll
  for (int f = 0; f < 2; ++f)
    offB[f] = 4096 + swz((wc * 32 + f * 16 + (lane & 15)) * 64 + q * 16);

  bf16x8 mnf[2][2];
  #pragma unroll
  for (int fi = 0; fi < 2; ++fi) {
    const u16* mp_ = mn + (size_t)(s * N_DIM + i0 + wr * 32 + fi * 16
                                   + (lane & 15)) * DM + q * 8;
    mnf[fi][0] = ld8(mp_);
    mnf[fi][1] = ld8(mp_ + 32);
  }

  f32x4 acc[2][2];
  f32x4 oacc[4][2];
  #pragma unroll
  for (int a = 0; a < 2; ++a)
    #pragma unroll
    for (int b = 0; b < 2; ++b) acc[a][b] = (f32x4){0.f, 0.f, 0.f, 0.f};
  #pragma unroll
  for (int a = 0; a < 4; ++a)
    #pragma unroll
    for (int b = 0; b < 2; ++b) oacc[a][b] = (f32x4){0.f, 0.f, 0.f, 0.f};

  const char* gA = (const char*)(wf + (size_t)i0 * 32);
  const char* gB = (const char*)(vf + (size_t)n0 * 32);

#define STAGE_P(pA_, pB_, slot)                                            \
  do {                                                                     \
    char* dA_ = (char*)&ring[(slot)][0];                                   \
    gload_lds16((pA_) + soA, dA_ + sbA);                                   \
    gload_lds16((pB_) + soB, dA_ + 4096 + sbA);                            \
  } while (0)

#define COMPUTE(slot)                                                      \
  do {                                                                     \
    const char* cS_ = (const char*)&ring[(slot)][0];                       \
    bf16x8 af_[2], bf_[2];                                                 \
    _Pragma("unroll")                                                      \
    for (int f = 0; f < 2; ++f) af_[f] = ld8((const u16*)(cS_ + offA[f])); \
    _Pragma("unroll")                                                      \
    for (int f = 0; f < 2; ++f) bf_[f] = ld8((const u16*)(cS_ + offB[f])); \
    __builtin_amdgcn_s_setprio(1);                                         \
    _Pragma("unroll")                                                      \
    for (int fi = 0; fi < 2; ++fi)                                         \
      _Pragma("unroll")                                                    \
      for (int fn = 0; fn < 2; ++fn)                                       \
        acc[fi][fn] = mfma16(bf_[fn], af_[fi], acc[fi][fn]);               \
    __builtin_amdgcn_s_setprio(0);                                         \
  } while (0)

#define INTERLUDE(hh)                                                      \
  do {                                                                     \
    bf16x8 wg_[2][2];                                                      \
    _Pragma("unroll")                                                      \
    for (int k2 = 0; k2 < 2; ++k2)                                         \
      _Pragma("unroll")                                                    \
      for (int kk = 0; kk < 2; ++kk)                                       \
        wg_[k2][kk] = ld8(wmg + ((16 + (hh) * 2 + k2) * 2 + kk) * 512 + lane * 8); \
    u16* bb_ = &ring[2][0] + wv * 1024;                                    \
    _Pragma("unroll")                                                      \
    for (int fi = 0; fi < 2; ++fi) {                                       \
      const int row_ = fi * 16 + (lane & 15);                              \
      const int sw_ = (row_ & 3) << 3;                                     \
      _Pragma("unroll")                                                    \
      for (int fn = 0; fn < 2; ++fn) {                                     \
        f32x4 ga_ = (f32x4){0.f, 0.f, 0.f, 0.f};                           \
        ga_ = mfma16(wg_[fn][0], mnf[fi][0], ga_);                         \
        ga_ = mfma16(wg_[fn][1], mnf[fi][1], ga_);                         \
        ushort4 pk_;                                                       \
        pk_.x = f2bf(acc[fi][fn][0] * fast_sigmoid(ga_[0]));               \
        pk_.y = f2bf(acc[fi][fn][1] * fast_sigmoid(ga_[1]));               \
        pk_.z = f2bf(acc[fi][fn][2] * fast_sigmoid(ga_[2]));               \
        pk_.w = f2bf(acc[fi][fn][3] * fast_sigmoid(ga_[3]));               \
        *(ushort4*)(bb_ + row_ * 32 + ((fn * 16 + q * 4) ^ sw_)) = pk_;    \
        acc[fi][fn] = (f32x4){0.f, 0.f, 0.f, 0.f};                         \
      }                                                                    \
    }                                                                      \
    asm volatile("s_waitcnt lgkmcnt(0)" ::: "memory");                     \
    __builtin_amdgcn_sched_barrier(0);                                     \
    bf16x8 ogf_[2], wo_[4];                                                \
    _Pragma("unroll")                                                      \
    for (int fi = 0; fi < 2; ++fi) {                                       \
      const int row_ = fi * 16 + (lane & 15);                              \
      ogf_[fi] = ld8(bb_ + row_ * 32 + ((q * 8) ^ ((row_ & 3) << 3)));     \
    }                                                                      \
    _Pragma("unroll")                                                      \
    for (int cn = 0; cn < 4; ++cn)                                         \
      wo_[cn] = ld8(wof + ((cn * 8 + (hh)) * 64 + lane) * 8);              \
    _Pragma("unroll")                                                      \
    for (int cn = 0; cn < 4; ++cn)                                         \
      _Pragma("unroll")                                                    \
      for (int fi = 0; fi < 2; ++fi)                                       \
        oacc[cn][fi] = mfma16(wo_[cn], ogf_[fi], oacc[cn][fi]);            \
  } while (0)

  STAGE_P(gA, gB, 0);
  STAGE_P(gA + 32768, gB + 524288, 1);

  for (int ho = 0; ho < 7; ++ho) {
    const char* pAh = gA + (size_t)(ho * 16) * 32768;
    const char* pBh = gB + (size_t)(ho * 16) * 524288;
    #pragma unroll
    for (int u = 0; u < 16; ++u) {
      asm volatile("s_waitcnt vmcnt(2)" ::: "memory");
      BARRIER();
      STAGE_P(pAh + (size_t)(u + 2) * 32768, pBh + (size_t)(u + 2) * 524288,
              (u + 2) & 3);
      COMPUTE(u & 3);
    }
    INTERLUDE(ho);
  }
  {
    const char* pAh = gA + (size_t)112 * 32768;
    const char* pBh = gB + (size_t)112 * 524288;
    #pragma unroll
    for (int u = 0; u < 14; ++u) {
      asm volatile("s_waitcnt vmcnt(2)" ::: "memory");
      BARRIER();
      STAGE_P(pAh + (size_t)(u + 2) * 32768, pBh + (size_t)(u + 2) * 524288,
              (u + 2) & 3);
      COMPUTE(u & 3);
    }
    asm volatile("s_waitcnt vmcnt(2)" ::: "memory");
    BARRIER();
    COMPUTE(2);
    asm volatile("s_waitcnt vmcnt(0)" ::: "memory");
    BARRIER();
    COMPUTE(3);
    INTERLUDE(7);
  }
#undef STAGE_P
#undef COMPUTE
#undef INTERLUDE

  #pragma unroll
  for (int cn = 0; cn < 4; ++cn) {
    #pragma unroll
    for (int fi = 0; fi < 2; ++fi) {
      float* op = out + (size_t)(s * N_DIM + i0 + wr * 32 + fi * 16
                                 + (lane & 15)) * DM + cn * 16 + q * 4;
      *(f32x4*)op = oacc[cn][fi];
    }
  }
}

extern "C" void kernel_launch(void* const* d_in, const int* in_sizes, int n_in,
                              void* d_out, int out_size, void* d_ws, size_t ws_size,
                              hipStream_t stream) {
  const float* m   = (const float*)d_in[0];
  const float* z   = (const float*)d_in[1];
  const float* mnw = (const float*)d_in[2];
  const float* mnb = (const float*)d_in[3];
  const float* znw = (const float*)d_in[4];
  const float* znb = (const float*)d_in[5];
  const float* Wm  = (const float*)d_in[6];
  const float* Wg  = (const float*)d_in[7];
  const float* Wz  = (const float*)d_in[8];
  const float* Wo  = (const float*)d_in[9];
  float* out = (float*)d_out;
  char* ws = (char*)d_ws;

  // ws layout (bytes): wf 4MiB | vf 64MiB | (free 64MiB) | mn 16MiB |
  //                    wmg 64KiB | wof 32KiB | wzf 8KiB | t1c 64B
  u16*   wbuf = (u16*)(ws);
  u16*   vf   = (u16*)(ws + ((size_t)4   << 20));
  u16*   mn   = (u16*)(ws + ((size_t)132 << 20));
  u16*   wmg  = (u16*)(ws + ((size_t)148 << 20));
  u16*   wof  = (u16*)(ws + ((size_t)148 << 20) + 65536);
  u16*   wzf  = (u16*)(ws + ((size_t)148 << 20) + 98304);
  float* t1c  = (float*)(ws + ((size_t)148 << 20) + 106496);

  k0_prep<<<209, 256, 0, stream>>>(Wm, Wg, Wo, znw, znb, Wz, wmg, wof, wzf, t1c);
  k1_fused<<<512, 512, 0, stream>>>(z, wzf, t1c, wbuf);
  k2_fused<<<1024, 512, 0, stream>>>(m, mnw, mnb, wmg, mn, vf);
  k3_fused<<<1024, 256, 0, stream>>>(wbuf, vf, mn, wmg, wof, out);
}

// Round 19
// 121.753 us; speedup vs baseline: 1.0552x; 1.0552x over previous
//
#include <hip/hip_runtime.h>

// PairWeightedAveraging: m[1,S,N,Dm], z[1,N,N,Dz] -> out[1,S,N,Dm]
// S=256 N=512 Dm=64 Dz=128 H=8 HD=32
// Pipeline (all bf16 MFMA):
//  k0: pre-swizzle [Wm|Wg], Wo, and W'=znw*Wz (split hi/lo bf16) frag tables
//  k12_fused: FAT kernel, 512 threads/block: blocks 0..511 run the k1 body
//    (bias MFMA in LDS + row softmax -> wf; 8 waves -> 4 j-passes, softmax =
//    one head per wave); blocks 512..1535 run the k2 body (LN(m) in-register
//    + v = mn @ Wm, 8 wave-groups/block).
//  k3_fused: verified-best (4-slot ring, static slots, bounce in slot 2,
//    32KB LDS, 4 blk/CU, vmcnt(2)).
//  R18->R19: REVERT to R17 verified-best (121.9us). R18's split + LDS-staged
//  vf write regressed (+6.6us): split lost k1/k2 overlap; vf scatter was only
//  ~2x write-inflated (not 8x), and the 69KB LDS tile halved k2 occupancy.

#define S_DIM 256
#define N_DIM 512
#define DM 64
#define DZ 128
#define NH 8
#define HD 32
#define HK 256
#define NP 8192  // S_DIM*HD
#define BKP 32   // K-panel depth
#define JT_N 16  // 512 / BKP

typedef unsigned int   u32;
typedef unsigned short u16;
typedef __bf16 bf16x8 __attribute__((ext_vector_type(8)));
typedef float  f32x4  __attribute__((ext_vector_type(4)));
typedef u32    u32x4  __attribute__((ext_vector_type(4)));

__device__ __forceinline__ u16 f2bf(float f) {
  u32 u = __builtin_bit_cast(u32, f);
  return (u16)((u + 0x7FFFu + ((u >> 16) & 1u)) >> 16);  // RNE
}
__device__ __forceinline__ float bf2f(u16 h) {
  u32 u = ((u32)h) << 16;
  return __builtin_bit_cast(float, u);
}
__device__ __forceinline__ u32 pack2(float a, float b) {
  return (u32)f2bf(a) | ((u32)f2bf(b) << 16);
}
__device__ __forceinline__ bf16x8 ld8(const u16* p) {
  return __builtin_bit_cast(bf16x8, *(const u32x4*)p);
}
__device__ __forceinline__ f32x4 mfma16(bf16x8 a, bf16x8 b, f32x4 c) {
  return __builtin_amdgcn_mfma_f32_16x16x32_bf16(a, b, c, 0, 0, 0);
}
__device__ __forceinline__ void gload_lds16(const void* gsrc, void* ldst) {
  __builtin_amdgcn_global_load_lds(
      (const __attribute__((address_space(1))) void*)gsrc,
      (__attribute__((address_space(3))) void*)ldst, 16, 0, 0);
}
__device__ __forceinline__ float fast_sigmoid(float x) {
  float r;
  asm("v_rcp_f32 %0, %1" : "=v"(r) : "v"(1.f + __expf(-x)));
  return r;
}
// panel byte-offset swizzle (involution; permutes 16B chunks within 8 rows of 64B)
__device__ __forceinline__ int swz(int lin) { return lin ^ (((lin >> 7) & 3) << 4); }

#define BARRIER() do { asm volatile("" ::: "memory"); \
                       __builtin_amdgcn_s_barrier();  \
                       asm volatile("" ::: "memory"); } while (0)

// ---------------- k0: weight fragment tables ----------------
// wmg: [cb(32)][ks(2)][lane(64)][t(8)]  c=cb*16+(lane&15), k=ks*32+(lane>>4)*8+t
// wof: [cb(4)][ks(8)][lane(64)][t(8)]   c=cb*16+(lane&15), hk=ks*32+(lane>>4)*8+t
// wzf: [ks(4)][p(2)][lane(64)][t(8)]    h=lane&15 (<8), k=ks*32+(lane>>4)*8+t
// t1c: [0..7]=t1[h]=sum_c W'[c][h]; [8..15]=cst[h]=sum_c znb[c]*Wz[c][h]
__global__ __launch_bounds__(256) void k0_prep(
    const float* __restrict__ Wm, const float* __restrict__ Wg,
    const float* __restrict__ Wo, const float* __restrict__ znw,
    const float* __restrict__ znb, const float* __restrict__ Wz,
    u16* __restrict__ wmg, u16* __restrict__ wof,
    u16* __restrict__ wzf, float* __restrict__ t1c) {
  const int idx = blockIdx.x * 256 + threadIdx.x;
  if (idx < 32768) {
    const int t = idx & 7, lane = (idx >> 3) & 63, ks = (idx >> 9) & 1, cb = idx >> 10;
    const int c = cb * 16 + (lane & 15);
    const int k = ks * 32 + ((lane >> 4) & 3) * 8 + t;
    const float v = (c < HK) ? Wm[k * HK + c] : Wg[k * HK + (c - HK)];
    wmg[idx] = f2bf(v);
  } else if (idx < 32768 + 16384) {
    const int j = idx - 32768;
    const int t = j & 7, lane = (j >> 3) & 63, ks = (j >> 9) & 7, cb = j >> 12;
    const int c = cb * 16 + (lane & 15);
    const int hk = ks * 32 + ((lane >> 4) & 3) * 8 + t;
    wof[j] = f2bf(Wo[hk * DM + c]);
  } else if (idx < 49152 + 4096) {
    const int q = idx - 49152;
    const int t = q & 7, lane = (q >> 3) & 63, p = (q >> 9) & 1, ks = q >> 10;
    const int h = lane & 15;
    const int k = ks * 32 + ((lane >> 4) & 3) * 8 + t;
    u16 val = 0;
    if (h < NH) {
      const float wp = znw[k] * Wz[k * NH + h];
      const u16 hi = f2bf(wp);
      val = (p == 0) ? hi : f2bf(wp - bf2f(hi));
    }
    wzf[q] = val;
  } else if (idx < 49152 + 4096 + 16) {
    const int q = idx - 49152 - 4096;  // 0..15
    const int h = q & 7;
    float s = 0.f;
    for (int c = 0; c < DZ; ++c)
      s += ((q < 8) ? znw[c] : znb[c]) * Wz[c * NH + h];
    t1c[q] = s;
  }
}

// ---------------- k12_fused: 512 threads; k1 body (0..511) + k2 (512..1535) --
__global__ __launch_bounds__(512, 4) void k12_fused(
    const float* __restrict__ z, const u16* __restrict__ wzf,
    const float* __restrict__ t1c, u16* __restrict__ wout,
    const float* __restrict__ m, const float* __restrict__ mnw,
    const float* __restrict__ mnb, const u16* __restrict__ wmg,
    u16* __restrict__ mn, u16* __restrict__ vf) {
  __shared__ __attribute__((aligned(16))) float sB[NH][N_DIM + 4];
  const int tid = threadIdx.x, lane = tid & 63, wv = tid >> 6;  // wv 0..7

  if (blockIdx.x < 512) {
    // ================= k1 body: bias MFMA in LDS + row softmax =============
    // 8 waves x 16 rows = 128 rows/pass, 4 passes.
    const int i = blockIdx.x;
    const int h16 = lane & 15;
    const float t1 = t1c[h16 & 7], cst = t1c[8 + (h16 & 7)];

    for (int jj = 0; jj < 4; ++jj) {
      const float* zp = z + ((size_t)i * N_DIM + jj * 128 + wv * 16
                             + (lane & 15)) * DZ + ((lane >> 4) & 3) * 8;
      f32x4 acc = (f32x4){0.f, 0.f, 0.f, 0.f};
      float sum = 0.f, sq = 0.f;
      #pragma unroll
      for (int ks = 0; ks < 4; ++ks) {
        const float4 v0 = *(const float4*)(zp + ks * 32);
        const float4 v1 = *(const float4*)(zp + ks * 32 + 4);
        const float xs[8] = {v0.x, v0.y, v0.z, v0.w, v1.x, v1.y, v1.z, v1.w};
        bf16x8 zh, zl;
        #pragma unroll
        for (int t = 0; t < 8; ++t) {
          sum += xs[t]; sq += xs[t] * xs[t];
          const u16 hv = f2bf(xs[t]);
          ((u16*)&zh)[t] = hv;
          ((u16*)&zl)[t] = f2bf(xs[t] - bf2f(hv));
        }
        const bf16x8 wh = ld8(wzf + (ks * 2 + 0) * 512 + lane * 8);
        const bf16x8 wl = ld8(wzf + (ks * 2 + 1) * 512 + lane * 8);
        acc = mfma16(zh, wh, acc);
        acc = mfma16(zl, wh, acc);
        acc = mfma16(zh, wl, acc);
      }
      sum += __shfl_xor(sum, 16, 64); sum += __shfl_xor(sum, 32, 64);
      sq  += __shfl_xor(sq, 16, 64);  sq  += __shfl_xor(sq, 32, 64);
      const float mu = sum * (1.f / DZ);
      const float rs = rsqrtf(sq * (1.f / DZ) - mu * mu + 1e-5f);
      #pragma unroll
      for (int rg = 0; rg < 4; ++rg) {
        const int r = ((lane >> 4) & 3) * 4 + rg;
        const float mur = __shfl(mu, r, 64);
        const float rsr = __shfl(rs, r, 64);
        const float bv = rsr * (acc[rg] - mur * t1) + cst;
        if (h16 < NH) sB[h16][jj * 128 + wv * 16 + r] = bv;
      }
    }
    __syncthreads();

    // softmax: wave wv handles head wv; lane owns j=lane*8..+8
    {
      const int h = wv;
      const float* bp = &sB[h][lane * 8];
      const float4 v0 = *(const float4*)bp;
      const float4 v1 = *(const float4*)(bp + 4);
      float xs[8] = {v0.x, v0.y, v0.z, v0.w, v1.x, v1.y, v1.z, v1.w};
      float mx = xs[0];
      #pragma unroll
      for (int t = 1; t < 8; ++t) mx = fmaxf(mx, xs[t]);
      #pragma unroll
      for (int off = 32; off; off >>= 1) mx = fmaxf(mx, __shfl_xor(mx, off, 64));
      float sm = 0.f;
      #pragma unroll
      for (int t = 0; t < 8; ++t) { xs[t] = __expf(xs[t] - mx); sm += xs[t]; }
      #pragma unroll
      for (int off = 32; off; off >>= 1) sm += __shfl_xor(sm, off, 64);
      const float inv = 1.f / sm;
      u32x4 pk;
      pk[0] = pack2(xs[0] * inv, xs[1] * inv);
      pk[1] = pack2(xs[2] * inv, xs[3] * inv);
      pk[2] = pack2(xs[4] * inv, xs[5] * inv);
      pk[3] = pack2(xs[6] * inv, xs[7] * inv);
      *(u32x4*)(wout + (((size_t)(h * JT_N + (lane >> 2)) * N_DIM + i) << 5)
                + (lane & 3) * 8) = pk;
    }
  } else {
    // ================= k2 body: LN(m) in-register + v = mn @ Wm ============
    float* swt = &sB[0][0];
    float* sbs = &sB[0][64];
    if (tid < DM) { swt[tid] = mnw[tid]; sbs[tid] = mnb[tid]; }
    __syncthreads();
    const int q = (lane >> 4) & 3;
    const int rbase = ((blockIdx.x - 512) * 8 + wv) * 16;
    const int r = rbase + (lane & 15);

    const float* mp = m + (size_t)r * DM + q * 8;
    const float4 va = *(const float4*)(mp);
    const float4 vb = *(const float4*)(mp + 4);
    const float4 vc = *(const float4*)(mp + 32);
    const float4 vd = *(const float4*)(mp + 36);
    const float x0[8] = {va.x, va.y, va.z, va.w, vb.x, vb.y, vb.z, vb.w};
    const float x1[8] = {vc.x, vc.y, vc.z, vc.w, vd.x, vd.y, vd.z, vd.w};
    float sum = 0.f, sq = 0.f;
    #pragma unroll
    for (int t = 0; t < 8; ++t) {
      sum += x0[t] + x1[t];
      sq  += x0[t] * x0[t] + x1[t] * x1[t];
    }
    sum += __shfl_xor(sum, 16, 64); sum += __shfl_xor(sum, 32, 64);
    sq  += __shfl_xor(sq, 16, 64);  sq  += __shfl_xor(sq, 32, 64);
    const float mu = sum * (1.f / DM);
    const float rs = rsqrtf(sq * (1.f / DM) - mu * mu + 1e-5f);

    bf16x8 a0, a1;
    #pragma unroll
    for (int t = 0; t < 8; ++t) {
      const int c0 = q * 8 + t, c1 = q * 8 + 32 + t;
      ((u16*)&a0)[t] = f2bf((x0[t] - mu) * rs * swt[c0] + sbs[c0]);
      ((u16*)&a1)[t] = f2bf((x1[t] - mu) * rs * swt[c1] + sbs[c1]);
    }
    *(u32x4*)(mn + (size_t)r * DM + q * 8)      = __builtin_bit_cast(u32x4, a0);
    *(u32x4*)(mn + (size_t)r * DM + q * 8 + 32) = __builtin_bit_cast(u32x4, a1);

    const u16* bp = wmg + lane * 8;
    const int r0 = rbase + ((lane >> 4) & 3) * 4;
    const int s0 = r0 >> 9;
    const int j0 = r0 & 511;

    f32x4 acc[16];
    #pragma unroll
    for (int cb = 0; cb < 16; ++cb) acc[cb] = (f32x4){0.f, 0.f, 0.f, 0.f};
    #pragma unroll
    for (int cb = 0; cb < 16; ++cb) {
      acc[cb] = mfma16(a0, ld8(bp + cb * 1024), acc[cb]);
      acc[cb] = mfma16(a1, ld8(bp + cb * 1024 + 512), acc[cb]);
    }
    #pragma unroll
    for (int cb = 0; cb < 16; ++cb) {
      const int c = cb * 16 + (lane & 15);
      const int h = c >> 5, k = c & 31;
      const int np = s0 * HD + k;
      const size_t idx = (((size_t)(h * JT_N + (j0 >> 5)) * NP + np) << 5) + (j0 & 31);
      ushort4 pk;
      pk.x = f2bf(acc[cb][0]); pk.y = f2bf(acc[cb][1]);
      pk.z = f2bf(acc[cb][2]); pk.w = f2bf(acc[cb][3]);
      *(ushort4*)(vf + idx) = pk;
    }
  }
}

// ---------------- k3_fused: o = w@v over all heads + gate + Wo projection ----
// UNCHANGED verified-best.
__global__ __launch_bounds__(256, 4) void k3_fused(
    const u16* __restrict__ wf, const u16* __restrict__ vf,
    const u16* __restrict__ mn, const u16* __restrict__ wmg,
    const u16* __restrict__ wof, float* __restrict__ out) {
  __shared__ __attribute__((aligned(16))) u16 ring[4][4096];  // 8KB/slot: A|B
  const int tid = threadIdx.x, lane = tid & 63, wv = tid >> 6;
  const int q = (lane >> 4) & 3;
  const int wr = wv >> 1, wc = wv & 1;
  const int bid = blockIdx.x;            // 0..1023
  const int xcd = bid & 7, j = bid >> 3; // j 0..127
  const int xt = xcd * 16 + (j >> 3);    // np-tile 0..127 (partitioned by XCD)
  const int yt = j & 7;                  // i-tile 0..7 (consecutive per panel)
  const int i0 = yt * 64;
  const int n0 = xt * 64;
  const int s  = xt * 2 + wc;

  const int sbA = wv * 1024;
  const int soA = swz(sbA + lane * 16);
  const int soB = swz(sbA + lane * 16);

  int offA[2], offB[2];
  #pragma unroll
  for (int f = 0; f < 2; ++f)
    offA[f] = swz((wr * 32 + f * 16 + (lane & 15)) * 64 + q * 16);
  #pragma unroll
  for (int f = 0; f < 2; ++f)
    offB[f] = 4096 + swz((wc * 32 + f * 16 + (lane & 15)) * 64 + q * 16);

  bf16x8 mnf[2][2];
  #pragma unroll
  for (int fi = 0; fi < 2; ++fi) {
    const u16* mp_ = mn + (size_t)(s * N_DIM + i0 + wr * 32 + fi * 16
                                   + (lane & 15)) * DM + q * 8;
    mnf[fi][0] = ld8(mp_);
    mnf[fi][1] = ld8(mp_ + 32);
  }

  f32x4 acc[2][2];
  f32x4 oacc[4][2];
  #pragma unroll
  for (int a = 0; a < 2; ++a)
    #pragma unroll
    for (int b = 0; b < 2; ++b) acc[a][b] = (f32x4){0.f, 0.f, 0.f, 0.f};
  #pragma unroll
  for (int a = 0; a < 4; ++a)
    #pragma unroll
    for (int b = 0; b < 2; ++b) oacc[a][b] = (f32x4){0.f, 0.f, 0.f, 0.f};

  const char* gA = (const char*)(wf + (size_t)i0 * 32);
  const char* gB = (const char*)(vf + (size_t)n0 * 32);

#define STAGE_P(pA_, pB_, slot)                                            \
  do {                                                                     \
    char* dA_ = (char*)&ring[(slot)][0];                                   \
    gload_lds16((pA_) + soA, dA_ + sbA);                                   \
    gload_lds16((pB_) + soB, dA_ + 4096 + sbA);                            \
  } while (0)

#define COMPUTE(slot)                                                      \
  do {                                                                     \
    const char* cS_ = (const char*)&ring[(slot)][0];                       \
    bf16x8 af_[2], bf_[2];                                                 \
    _Pragma("unroll")                                                      \
    for (int f = 0; f < 2; ++f) af_[f] = ld8((const u16*)(cS_ + offA[f])); \
    _Pragma("unroll")                                                      \
    for (int f = 0; f < 2; ++f) bf_[f] = ld8((const u16*)(cS_ + offB[f])); \
    __builtin_amdgcn_s_setprio(1);                                         \
    _Pragma("unroll")                                                      \
    for (int fi = 0; fi < 2; ++fi)                                         \
      _Pragma("unroll")                                                    \
      for (int fn = 0; fn < 2; ++fn)                                       \
        acc[fi][fn] = mfma16(bf_[fn], af_[fi], acc[fi][fn]);               \
    __builtin_amdgcn_s_setprio(0);                                         \
  } while (0)

#define INTERLUDE(hh)                                                      \
  do {                                                                     \
    bf16x8 wg_[2][2];                                                      \
    _Pragma("unroll")                                                      \
    for (int k2 = 0; k2 < 2; ++k2)                                         \
      _Pragma("unroll")                                                    \
      for (int kk = 0; kk < 2; ++kk)                                       \
        wg_[k2][kk] = ld8(wmg + ((16 + (hh) * 2 + k2) * 2 + kk) * 512 + lane * 8); \
    u16* bb_ = &ring[2][0] + wv * 1024;                                    \
    _Pragma("unroll")                                                      \
    for (int fi = 0; fi < 2; ++fi) {                                       \
      const int row_ = fi * 16 + (lane & 15);                              \
      const int sw_ = (row_ & 3) << 3;                                     \
      _Pragma("unroll")                                                    \
      for (int fn = 0; fn < 2; ++fn) {                                     \
        f32x4 ga_ = (f32x4){0.f, 0.f, 0.f, 0.f};                           \
        ga_ = mfma16(wg_[fn][0], mnf[fi][0], ga_);                         \
        ga_ = mfma16(wg_[fn][1], mnf[fi][1], ga_);                         \
        ushort4 pk_;                                                       \
        pk_.x = f2bf(acc[fi][fn][0] * fast_sigmoid(ga_[0]));               \
        pk_.y = f2bf(acc[fi][fn][1] * fast_sigmoid(ga_[1]));               \
        pk_.z = f2bf(acc[fi][fn][2] * fast_sigmoid(ga_[2]));               \
        pk_.w = f2bf(acc[fi][fn][3] * fast_sigmoid(ga_[3]));               \
        *(ushort4*)(bb_ + row_ * 32 + ((fn * 16 + q * 4) ^ sw_)) = pk_;    \
        acc[fi][fn] = (f32x4){0.f, 0.f, 0.f, 0.f};                         \
      }                                                                    \
    }                                                                      \
    asm volatile("s_waitcnt lgkmcnt(0)" ::: "memory");                     \
    __builtin_amdgcn_sched_barrier(0);                                     \
    bf16x8 ogf_[2], wo_[4];                                                \
    _Pragma("unroll")                                                      \
    for (int fi = 0; fi < 2; ++fi) {                                       \
      const int row_ = fi * 16 + (lane & 15);                              \
      ogf_[fi] = ld8(bb_ + row_ * 32 + ((q * 8) ^ ((row_ & 3) << 3)));     \
    }                                                                      \
    _Pragma("unroll")                                                      \
    for (int cn = 0; cn < 4; ++cn)                                         \
      wo_[cn] = ld8(wof + ((cn * 8 + (hh)) * 64 + lane) * 8);              \
    _Pragma("unroll")                                                      \
    for (int cn = 0; cn < 4; ++cn)                                         \
      _Pragma("unroll")                                                    \
      for (int fi = 0; fi < 2; ++fi)                                       \
        oacc[cn][fi] = mfma16(wo_[cn], ogf_[fi], oacc[cn][fi]);            \
  } while (0)

  STAGE_P(gA, gB, 0);
  STAGE_P(gA + 32768, gB + 524288, 1);

  for (int ho = 0; ho < 7; ++ho) {
    const char* pAh = gA + (size_t)(ho * 16) * 32768;
    const char* pBh = gB + (size_t)(ho * 16) * 524288;
    #pragma unroll
    for (int u = 0; u < 16; ++u) {
      asm volatile("s_waitcnt vmcnt(2)" ::: "memory");
      BARRIER();
      STAGE_P(pAh + (size_t)(u + 2) * 32768, pBh + (size_t)(u + 2) * 524288,
              (u + 2) & 3);
      COMPUTE(u & 3);
    }
    INTERLUDE(ho);
  }
  {
    const char* pAh = gA + (size_t)112 * 32768;
    const char* pBh = gB + (size_t)112 * 524288;
    #pragma unroll
    for (int u = 0; u < 14; ++u) {
      asm volatile("s_waitcnt vmcnt(2)" ::: "memory");
      BARRIER();
      STAGE_P(pAh + (size_t)(u + 2) * 32768, pBh + (size_t)(u + 2) * 524288,
              (u + 2) & 3);
      COMPUTE(u & 3);
    }
    asm volatile("s_waitcnt vmcnt(2)" ::: "memory");
    BARRIER();
    COMPUTE(2);
    asm volatile("s_waitcnt vmcnt(0)" ::: "memory");
    BARRIER();
    COMPUTE(3);
    INTERLUDE(7);
  }
#undef STAGE_P
#undef COMPUTE
#undef INTERLUDE

  #pragma unroll
  for (int cn = 0; cn < 4; ++cn) {
    #pragma unroll
    for (int fi = 0; fi < 2; ++fi) {
      float* op = out + (size_t)(s * N_DIM + i0 + wr * 32 + fi * 16
                                 + (lane & 15)) * DM + cn * 16 + q * 4;
      *(f32x4*)op = oacc[cn][fi];
    }
  }
}

extern "C" void kernel_launch(void* const* d_in, const int* in_sizes, int n_in,
                              void* d_out, int out_size, void* d_ws, size_t ws_size,
                              hipStream_t stream) {
  const float* m   = (const float*)d_in[0];
  const float* z   = (const float*)d_in[1];
  const float* mnw = (const float*)d_in[2];
  const float* mnb = (const float*)d_in[3];
  const float* znw = (const float*)d_in[4];
  const float* znb = (const float*)d_in[5];
  const float* Wm  = (const float*)d_in[6];
  const float* Wg  = (const float*)d_in[7];
  const float* Wz  = (const float*)d_in[8];
  const float* Wo  = (const float*)d_in[9];
  float* out = (float*)d_out;
  char* ws = (char*)d_ws;

  // ws layout (bytes): wf 4MiB | vf 64MiB | (free 64MiB) | mn 16MiB |
  //                    wmg 64KiB | wof 32KiB | wzf 8KiB | t1c 64B
  u16*   wbuf = (u16*)(ws);
  u16*   vf   = (u16*)(ws + ((size_t)4   << 20));
  u16*   mn   = (u16*)(ws + ((size_t)132 << 20));
  u16*   wmg  = (u16*)(ws + ((size_t)148 << 20));
  u16*   wof  = (u16*)(ws + ((size_t)148 << 20) + 65536);
  u16*   wzf  = (u16*)(ws + ((size_t)148 << 20) + 98304);
  float* t1c  = (float*)(ws + ((size_t)148 << 20) + 106496);

  k0_prep<<<209, 256, 0, stream>>>(Wm, Wg, Wo, znw, znb, Wz, wmg, wof, wzf, t1c);
  k12_fused<<<1536, 512, 0, stream>>>(z, wzf, t1c, wbuf, m, mnw, mnb, wmg, mn, vf);
  k3_fused<<<1024, 256, 0, stream>>>(wbuf, vf, mn, wmg, wof, out);
}